// Round 8
// baseline (694.400 us; speedup 1.0000x reference)
//
#include <hip/hip_runtime.h>

#define B_ 2
#define L_ 2048
#define HEADS_ 16
#define DH_ 64
#define DM_ 1024
#define DBI_ 2048
#define DPROJ_ 7168
#define NTOK (B_*L_)      // 4096
#define DCAT (DM_ + DBI_) // 3072

typedef __bf16 bf16;
typedef __attribute__((ext_vector_type(4))) __bf16 bf16x4;
typedef __attribute__((ext_vector_type(8))) __bf16 bf16x8;
typedef __attribute__((ext_vector_type(4))) float floatx4;

typedef __attribute__((address_space(1))) const void gptr_t;
typedef __attribute__((address_space(3))) void lptr_t;

__device__ __forceinline__ void g2l16(const void* g, void* l) {
    __builtin_amdgcn_global_load_lds((gptr_t*)g, (lptr_t*)l, 16, 0, 0);
}

// ---------------- fused weight transposes: w_in + w_out -> bf16 T ----------------
__global__ __launch_bounds__(256) void transpose_both(const float* __restrict__ w_in,
                                                      const float* __restrict__ w_out,
                                                      bf16* __restrict__ w_inT,
                                                      bf16* __restrict__ w_outT) {
    __shared__ float tile[32][33];
    int l = blockIdx.x;
    const float* in; bf16* outp; int R, C, bx, by;
    if (l < 7168) { in = w_in;  outp = w_inT;  R = DM_;  C = DPROJ_; bx = l % 224; by = l / 224; }
    else { l -= 7168; in = w_out; outp = w_outT; R = DCAT; C = DM_;   bx = l % 32;  by = l / 32; }
    int c0 = bx * 32, r0 = by * 32;
    int x = threadIdx.x & 31, y = threadIdx.x >> 5;
    for (int i = 0; i < 32; i += 8)
        tile[y + i][x] = in[(size_t)(r0 + y + i) * C + (c0 + x)];
    __syncthreads();
    for (int i = 0; i < 32; i += 8)
        outp[(size_t)(c0 + y + i) * R + (r0 + x)] = (bf16)tile[x][y + i];
}

// ---------------- in-LN + token shift -> xs (bf16), float4 vectorized ----------------
__global__ __launch_bounds__(256) void ln_shift(const float* __restrict__ x,
                                                const float* __restrict__ g,
                                                const float* __restrict__ bb,
                                                bf16* __restrict__ xs) {
    int tok = blockIdx.x;
    int b = tok >> 11, l = tok & 2047;
    int t = threadIdx.x;
    float4 v = ((const float4*)(x + (size_t)tok * DM_))[t];
    float s = v.x + v.y + v.z + v.w;
    float s2 = v.x * v.x + v.y * v.y + v.z * v.z + v.w * v.w;
    __shared__ float red[2][4];
    for (int o = 32; o; o >>= 1) { s += __shfl_xor(s, o); s2 += __shfl_xor(s2, o); }
    int w = t >> 6;
    if ((t & 63) == 0) { red[0][w] = s; red[1][w] = s2; }
    __syncthreads();
    s  = red[0][0] + red[0][1] + red[0][2] + red[0][3];
    s2 = red[1][0] + red[1][1] + red[1][2] + red[1][3];
    float mean = s * (1.f / DM_);
    float var  = s2 * (1.f / DM_) - mean * mean;
    float rstd = rsqrtf(var + 1e-5f);
    int c = t * 4;
    float4 gg = ((const float4*)g)[t];
    float4 bv = ((const float4*)bb)[t];
    bf16x4 y;
    y[0] = (bf16)((v.x - mean) * rstd * gg.x + bv.x);
    y[1] = (bf16)((v.y - mean) * rstd * gg.y + bv.y);
    y[2] = (bf16)((v.z - mean) * rstd * gg.z + bv.z);
    y[3] = (bf16)((v.w - mean) * rstd * gg.w + bv.w);
    int shift = (c < 256) ? 1 : ((c >= 896) ? 2 : 0);
    int dl = l + shift;
    if (dl < L_) *(bf16x4*)&xs[((size_t)b * L_ + dl) * DM_ + c] = y;
    if (l == 0 && shift) {
        bf16x4 z = {};
        *(bf16x4*)&xs[((size_t)b * L_) * DM_ + c] = z;
        if (shift == 2) *(bf16x4*)&xs[((size_t)b * L_ + 1) * DM_ + c] = z;
    }
}

// ---------------- GEMM1: 256x128 tile, ping-pong dbuf, 3 blocks/CU ----------------
__global__ __launch_bounds__(256, 3) void gemm1_k(const bf16* __restrict__ A,
                                                  const bf16* __restrict__ Bt,
                                                  bf16* __restrict__ C) {
    const int K = DM_, N = DPROJ_;
    int lin = blockIdx.x;                 // 896 blocks
    int chunk = lin >> 7, within = lin & 127;
    int m0 = (within >> 3) * 256;
    int n0 = (chunk * 8 + (within & 7)) * 128;
    __shared__ bf16 As[2][256 * 32];
    __shared__ bf16 Bs[2][128 * 32];
    int t = threadIdx.x, lane = t & 63, wave = t >> 6;
    int c = lane & 15, quad = lane >> 4;
    int wm = wave * 64;
    auto stage = [&](int k0, int bsel) {
        #pragma unroll
        for (int s = 0; s < 4; s++) {
            int f = s * 256 + t;
            int row = f >> 2, kp = (f & 3) * 8;
            g2l16(A + (size_t)(m0 + row) * K + k0 + kp, &As[bsel][f * 8]);
        }
        #pragma unroll
        for (int s = 0; s < 2; s++) {
            int f = s * 256 + t;
            int row = f >> 2, kp = (f & 3) * 8;
            g2l16(Bt + (size_t)(n0 + row) * K + k0 + kp, &Bs[bsel][f * 8]);
        }
    };
    floatx4 acc[4][8] = {};
    stage(0, 0);
    int buf = 0;
    for (int k0 = 0; k0 < K; k0 += 32) {
        __syncthreads();
        if (k0 + 32 < K) stage(k0 + 32, buf ^ 1);
        bf16x8 af[4], bfr[8];
        #pragma unroll
        for (int i = 0; i < 4; i++)
            af[i] = *(const bf16x8*)&As[buf][(wm + i * 16 + c) * 32 + quad * 8];
        #pragma unroll
        for (int j = 0; j < 8; j++)
            bfr[j] = *(const bf16x8*)&Bs[buf][(j * 16 + c) * 32 + quad * 8];
        #pragma unroll
        for (int i = 0; i < 4; i++)
            #pragma unroll
            for (int j = 0; j < 8; j++)
                acc[i][j] = __builtin_amdgcn_mfma_f32_16x16x32_bf16(af[i], bfr[j], acc[i][j], 0, 0, 0);
        buf ^= 1;
    }
    #pragma unroll
    for (int i = 0; i < 4; i++)
        #pragma unroll
        for (int j = 0; j < 8; j++)
            #pragma unroll
            for (int r = 0; r < 4; r++) {
                int row = m0 + wm + i * 16 + quad * 4 + r;
                int col = n0 + j * 16 + c;
                C[(size_t)row * N + col] = (bf16)acc[i][j][r];
            }
}

// ---------------- GEMM2 split-K: 128x128, dbuf, 4 blocks/CU ----------------
__global__ __launch_bounds__(256, 4) void gemm2_sk(const bf16* __restrict__ A,
                                                   const bf16* __restrict__ Bt,
                                                   float* __restrict__ P) {
    const int ldA = DCAT, N = DM_;
    int m0 = blockIdx.x * 128, n0 = blockIdx.y * 128, kz = blockIdx.z;
    const bf16* Ak = A + kz * 1024;
    const bf16* Btk = Bt + kz * 1024;
    float* C = P + (size_t)kz * NTOK * DM_;
    __shared__ bf16 As[2][128 * 32];
    __shared__ bf16 Bs[2][128 * 32];
    int t = threadIdx.x, lane = t & 63, wave = t >> 6;
    int c = lane & 15, quad = lane >> 4;
    int wm = (wave >> 1) * 64, wn = (wave & 1) * 64;
    auto stage = [&](int k0, int bsel) {
        #pragma unroll
        for (int s = 0; s < 2; s++) {
            int f = s * 256 + t;
            int row = f >> 2, kp = (f & 3) * 8;
            g2l16(Ak + (size_t)(m0 + row) * ldA + k0 + kp, &As[bsel][f * 8]);
            g2l16(Btk + (size_t)(n0 + row) * ldA + k0 + kp, &Bs[bsel][f * 8]);
        }
    };
    floatx4 acc[4][4] = {};
    stage(0, 0);
    int buf = 0;
    for (int k0 = 0; k0 < 1024; k0 += 32) {
        __syncthreads();
        if (k0 + 32 < 1024) stage(k0 + 32, buf ^ 1);
        bf16x8 af[4], bfr[4];
        #pragma unroll
        for (int i = 0; i < 4; i++)
            af[i] = *(const bf16x8*)&As[buf][(wm + i * 16 + c) * 32 + quad * 8];
        #pragma unroll
        for (int j = 0; j < 4; j++)
            bfr[j] = *(const bf16x8*)&Bs[buf][(wn + j * 16 + c) * 32 + quad * 8];
        #pragma unroll
        for (int i = 0; i < 4; i++)
            #pragma unroll
            for (int j = 0; j < 4; j++)
                acc[i][j] = __builtin_amdgcn_mfma_f32_16x16x32_bf16(af[i], bfr[j], acc[i][j], 0, 0, 0);
        buf ^= 1;
    }
    #pragma unroll
    for (int i = 0; i < 4; i++)
        #pragma unroll
        for (int j = 0; j < 4; j++)
            #pragma unroll
            for (int r = 0; r < 4; r++) {
                int row = m0 + wm + i * 16 + quad * 4 + r;
                int col = n0 + wn + j * 16 + c;
                C[(size_t)row * N + col] = acc[i][j][r];
            }
}

// ---------------- mid-LN fused, vec8: h -> Qp,Kp,Vn packed + gated A2 ----------------
// Thread t owns vec8 chunks {t, t+256, t+512, (t<128: t+768)} of the 896-chunk
// row. p1 chunks pair with p2 chunks exactly 256 later -> gate is thread-local.
__global__ __launch_bounds__(256) void mid_ln_fused(const bf16* __restrict__ h,
                                                    const float* __restrict__ g,
                                                    const float* __restrict__ bb,
                                                    bf16* __restrict__ Qp,
                                                    bf16* __restrict__ Kp,
                                                    bf16* __restrict__ Vn,
                                                    bf16* __restrict__ A2) {
    int tok = blockIdx.x;
    int b = tok >> 11, l = tok & 2047;
    const bf16x8* hrow = (const bf16x8*)(h + (size_t)tok * DPROJ_);
    int t = threadIdx.x;
    int nch = (t < 128) ? 4 : 3;
    float v[4][8];
    float s = 0.f, s2 = 0.f;
    for (int i = 0; i < nch; i++) {
        bf16x8 hv = hrow[t + i * 256];
        #pragma unroll
        for (int j = 0; j < 8; j++) {
            float f = (float)hv[j];
            v[i][j] = f; s += f; s2 += f * f;
        }
    }
    __shared__ float red[2][4];
    for (int o = 32; o; o >>= 1) { s += __shfl_xor(s, o); s2 += __shfl_xor(s2, o); }
    int w = t >> 6;
    if ((t & 63) == 0) { red[0][w] = s; red[1][w] = s2; }
    __syncthreads();
    s  = red[0][0] + red[0][1] + red[0][2] + red[0][3];
    s2 = red[1][0] + red[1][1] + red[1][2] + red[1][3];
    float mean = s * (1.f / DPROJ_);
    float var  = s2 * (1.f / DPROJ_) - mean * mean;
    float rstd = rsqrtf(var + 1e-5f);
    for (int i = 0; i < nch; i++) {
        int c = (t + i * 256) * 8;
        float4 g0 = *(const float4*)&g[c],  g1 = *(const float4*)&g[c + 4];
        float4 b0 = *(const float4*)&bb[c], b1 = *(const float4*)&bb[c + 4];
        v[i][0] = (v[i][0] - mean) * rstd * g0.x + b0.x;
        v[i][1] = (v[i][1] - mean) * rstd * g0.y + b0.y;
        v[i][2] = (v[i][2] - mean) * rstd * g0.z + b0.z;
        v[i][3] = (v[i][3] - mean) * rstd * g0.w + b0.w;
        v[i][4] = (v[i][4] - mean) * rstd * g1.x + b1.x;
        v[i][5] = (v[i][5] - mean) * rstd * g1.y + b1.y;
        v[i][6] = (v[i][6] - mean) * rstd * g1.z + b1.z;
        v[i][7] = (v[i][7] - mean) * rstd * g1.w + b1.w;
    }
    bf16x8 o;
    // chunk 0: Q (t<128) or K (t>=128)
    {
        int cc = (t < 128) ? t * 8 : (t - 128) * 8;
        int hh = cc >> 6, d = cc & 63;
        #pragma unroll
        for (int j = 0; j < 8; j++) o[j] = (bf16)v[0][j];
        bf16* dst = (t < 128) ? Qp : Kp;
        *(bf16x8*)&dst[(((size_t)b * HEADS_ + hh) * L_ + l) * DH_ + d] = o;
    }
    if (t < 128) {
        // chunk 1: V (c = 2048 + t*8)
        int cc = t * 8, hh = cc >> 6, d = cc & 63;
        #pragma unroll
        for (int j = 0; j < 8; j++) o[j] = (bf16)v[1][j];
        *(bf16x8*)&Vn[(((size_t)b * HEADS_ + hh) * L_ + l) * DH_ + d] = o;
        // gate: chunk2 (p1, cc=t*8+1024) * chunk3 (p2, same cc)
        #pragma unroll
        for (int j = 0; j < 8; j++) o[j] = (bf16)(v[2][j] * v[3][j]);
        *(bf16x8*)&A2[(size_t)tok * DCAT + DM_ + t * 8 + 1024] = o;
    } else {
        // gate: chunk1 (p1, cc=(t-128)*8) * chunk2 (p2, same cc)
        #pragma unroll
        for (int j = 0; j < 8; j++) o[j] = (bf16)(v[1][j] * v[2][j]);
        *(bf16x8*)&A2[(size_t)tok * DCAT + DM_ + (t - 128) * 8] = o;
    }
}

// ---------------- Vn [b,h,L,64] -> Vt [b,h,64,L] ----------------
__global__ __launch_bounds__(256) void vt_pack(const bf16* __restrict__ Vn,
                                               bf16* __restrict__ Vt) {
    __shared__ bf16 tile[32][33];
    int bh = blockIdx.z;
    const bf16* in = Vn + (size_t)bh * L_ * DH_;
    bf16* out = Vt + (size_t)bh * DH_ * L_;
    int l0 = blockIdx.x * 32, d0 = blockIdx.y * 32;
    int x = threadIdx.x & 31, y = threadIdx.x >> 5;
    for (int i = 0; i < 32; i += 8)
        tile[y + i][x] = in[(size_t)(l0 + y + i) * DH_ + d0 + x];
    __syncthreads();
    for (int i = 0; i < 32; i += 8)
        out[(size_t)(d0 + y + i) * L_ + l0 + x] = tile[x][y + i];
}

// ---------------- flash attention v4: fixed-max softmax ----------------
__global__ __launch_bounds__(256, 4) void attn4(const bf16* __restrict__ Qp,
                                                const bf16* __restrict__ Kp,
                                                const bf16* __restrict__ Vt,
                                                const float* __restrict__ slopes,
                                                bf16* __restrict__ A2) {
    int hd = blockIdx.y, b = blockIdx.z;
    int lin = blockIdx.x + 32 * blockIdx.y + 512 * blockIdx.z;
    int xr = blockIdx.x;
    int qt = ((lin >> 8) & 1) ? (31 - xr) : xr;
    int q0 = qt * 64;
    int t = threadIdx.x, lane = t & 63, wave = t >> 6;
    int quad = lane >> 4, c = lane & 15;
    __shared__ bf16 Ks[2 * 64 * 32];
    __shared__ bf16 Vs[2 * 64 * 32];
    __shared__ bf16 Ps[4][16 * 72];
    int bh = b * HEADS_ + hd;
    const bf16* Qb = Qp + (size_t)bh * L_ * DH_;
    const bf16* Kb = Kp + (size_t)bh * L_ * DH_;
    const bf16* Vb = Vt + (size_t)bh * DH_ * L_;
    const float LOG2E = 1.44269504f;
    float slopeL2 = slopes[hd] * LOG2E;
    const float qscale = 0.125f * LOG2E;

    bf16x8 qf[2];
    int qrow = q0 + wave * 16 + c;
    qf[0] = *(const bf16x8*)(Qb + (size_t)qrow * DH_ + quad * 8);
    qf[1] = *(const bf16x8*)(Qb + (size_t)qrow * DH_ + 32 + quad * 8);
    floatx4 accO[4] = {};
    float lsum[4];
    float mrow[4];
    int i_row0 = q0 + wave * 16 + quad * 4;
    #pragma unroll
    for (int r = 0; r < 4; r++) {
        lsum[r] = 0.f;
        mrow[r] = slopeL2 * (float)(i_row0 + r) + 20.0f;
    }

    int row = t >> 2, kp = (t & 3) * 8;
    bf16* pw = &Ps[wave][0];
    bf16* pwr = pw + (quad * 4) * 72 + c;
    for (int j0 = 0; j0 <= q0; j0 += 64) {
        #pragma unroll
        for (int s = 0; s < 2; s++) {
            g2l16(Kb + (size_t)(j0 + row) * DH_ + s * 32 + kp, &Ks[(s * 256 + t) * 8]);
            g2l16(Vb + (size_t)row * L_ + j0 + s * 32 + kp, &Vs[(s * 256 + t) * 8]);
        }
        __syncthreads();

        bool diag = (j0 == q0);
        #pragma unroll
        for (int nt = 0; nt < 4; nt++) {
            floatx4 sacc = {};
            bf16x8 kf0 = *(const bf16x8*)&Ks[(nt * 16 + c) * 32 + quad * 8];
            bf16x8 kf1 = *(const bf16x8*)&Ks[2048 + (nt * 16 + c) * 32 + quad * 8];
            sacc = __builtin_amdgcn_mfma_f32_16x16x32_bf16(qf[0], kf0, sacc, 0, 0, 0);
            sacc = __builtin_amdgcn_mfma_f32_16x16x32_bf16(qf[1], kf1, sacc, 0, 0, 0);
            int j = j0 + nt * 16 + c;
            float aj = slopeL2 * (float)j;
            #pragma unroll
            for (int r = 0; r < 4; r++) {
                float p = exp2f(fmaf(sacc[r], qscale, aj) - mrow[r]);
                if (diag) p = (j <= i_row0 + r) ? p : 0.f;
                lsum[r] += p;
                pwr[r * 72 + nt * 16] = (bf16)p;
            }
        }
        bf16x8 pf0 = *(const bf16x8*)&pw[c * 72 + quad * 8];
        bf16x8 pf1 = *(const bf16x8*)&pw[c * 72 + 32 + quad * 8];
        #pragma unroll
        for (int nt = 0; nt < 4; nt++) {
            bf16x8 vf0 = *(const bf16x8*)&Vs[(nt * 16 + c) * 32 + quad * 8];
            bf16x8 vf1 = *(const bf16x8*)&Vs[2048 + (nt * 16 + c) * 32 + quad * 8];
            accO[nt] = __builtin_amdgcn_mfma_f32_16x16x32_bf16(pf0, vf0, accO[nt], 0, 0, 0);
            accO[nt] = __builtin_amdgcn_mfma_f32_16x16x32_bf16(pf1, vf1, accO[nt], 0, 0, 0);
        }
        __syncthreads();
    }
    #pragma unroll
    for (int r = 0; r < 4; r++) {
        float l = lsum[r];
        l += __shfl_xor(l, 1);
        l += __shfl_xor(l, 2);
        l += __shfl_xor(l, 4);
        l += __shfl_xor(l, 8);
        lsum[r] = 1.f / l;
    }
    #pragma unroll
    for (int r = 0; r < 4; r++) {
        size_t orow = (size_t)b * L_ + q0 + wave * 16 + quad * 4 + r;
        #pragma unroll
        for (int nt = 0; nt < 4; nt++)
            A2[orow * DCAT + hd * DH_ + nt * 16 + c] = (bf16)(accO[nt][r] * lsum[r]);
    }
}

// ---------------- out-LN over sum of 3 contiguous split-K partials (float4) ----------------
__global__ __launch_bounds__(256) void out_ln3(const float* __restrict__ P,
                                               const float* __restrict__ g,
                                               const float* __restrict__ bb,
                                               float* __restrict__ out) {
    size_t base = (size_t)blockIdx.x * DM_;
    const size_t stride = (size_t)NTOK * DM_;
    int t = threadIdx.x;
    float4 a = *(const float4*)&P[base + t * 4];
    float4 b1 = *(const float4*)&P[base + stride + t * 4];
    float4 c1 = *(const float4*)&P[base + 2 * stride + t * 4];
    float4 v;
    v.x = a.x + b1.x + c1.x; v.y = a.y + b1.y + c1.y;
    v.z = a.z + b1.z + c1.z; v.w = a.w + b1.w + c1.w;
    float s = v.x + v.y + v.z + v.w;
    float s2 = v.x * v.x + v.y * v.y + v.z * v.z + v.w * v.w;
    __shared__ float red[2][4];
    for (int o = 32; o; o >>= 1) { s += __shfl_xor(s, o); s2 += __shfl_xor(s2, o); }
    int w = t >> 6;
    if ((t & 63) == 0) { red[0][w] = s; red[1][w] = s2; }
    __syncthreads();
    s  = red[0][0] + red[0][1] + red[0][2] + red[0][3];
    s2 = red[1][0] + red[1][1] + red[1][2] + red[1][3];
    float mean = s * (1.f / DM_);
    float var  = s2 * (1.f / DM_) - mean * mean;
    float rstd = rsqrtf(var + 1e-5f);
    float4 gg = ((const float4*)g)[t];
    float4 bv = ((const float4*)bb)[t];
    float4 y;
    y.x = (v.x - mean) * rstd * gg.x + bv.x;
    y.y = (v.y - mean) * rstd * gg.y + bv.y;
    y.z = (v.z - mean) * rstd * gg.z + bv.z;
    y.w = (v.w - mean) * rstd * gg.w + bv.w;
    *(float4*)&out[base + t * 4] = y;
}

extern "C" void kernel_launch(void* const* d_in, const int* in_sizes, int n_in,
                              void* d_out, int out_size, void* d_ws, size_t ws_size,
                              hipStream_t stream) {
    const float* x     = (const float*)d_in[0];
    const float* in_g  = (const float*)d_in[1];
    const float* in_b  = (const float*)d_in[2];
    const float* mid_g = (const float*)d_in[3];
    const float* mid_b = (const float*)d_in[4];
    const float* out_g = (const float*)d_in[5];
    const float* out_b = (const float*)d_in[6];
    const float* w_in  = (const float*)d_in[7];
    const float* w_out = (const float*)d_in[8];
    const float* slopes = (const float*)d_in[9];
    float* out = (float*)d_out;

    char* ws = (char*)d_ws;
    size_t off = 0;
    auto alloc = [&](size_t n) { char* p = ws + off; off += (n + 255) & ~(size_t)255; return p; };
    bf16* w_inT  = (bf16*)alloc((size_t)DPROJ_ * DM_ * 2);   // 14.7 MB
    bf16* w_outT = (bf16*)alloc((size_t)DM_ * DCAT * 2);     // 6.3 MB
    bf16* xs     = (bf16*)alloc((size_t)NTOK * DM_ * 2);     // 8.4 MB (reused as Vt)
    bf16* h      = (bf16*)alloc((size_t)NTOK * DPROJ_ * 2);  // 58.7 MB (reused: 3 contig f32 partials)
    bf16* A2     = (bf16*)alloc((size_t)NTOK * DCAT * 2);    // 25.2 MB
    bf16* Qp     = (bf16*)alloc((size_t)NTOK * DM_ * 2);     // 8.4 MB
    bf16* Kp     = (bf16*)alloc((size_t)NTOK * DM_ * 2);     // 8.4 MB
    bf16* Vn     = (bf16*)alloc((size_t)NTOK * DM_ * 2);     // 8.4 MB
    bf16* Vt = xs;            // xs dead after gemm1
    float* P = (float*)h;     // h dead after mid_ln_fused; gemm2 runs after attn

    hipLaunchKernelGGL(transpose_both, dim3(7168 + 3072), dim3(256), 0, stream,
                       w_in, w_out, w_inT, w_outT);
    hipLaunchKernelGGL(ln_shift, dim3(NTOK), dim3(256), 0, stream, x, in_g, in_b, xs);
    hipLaunchKernelGGL(gemm1_k, dim3(896), dim3(256), 0, stream, xs, w_inT, h);
    hipLaunchKernelGGL(mid_ln_fused, dim3(NTOK), dim3(256), 0, stream, h, mid_g, mid_b,
                       Qp, Kp, Vn, A2);
    hipLaunchKernelGGL(vt_pack, dim3(L_ / 32, DH_ / 32, B_ * HEADS_), dim3(256), 0, stream, Vn, Vt);
    hipLaunchKernelGGL(attn4, dim3(32, HEADS_, B_), dim3(256), 0, stream, Qp, Kp, Vt, slopes, A2);
    hipLaunchKernelGGL(gemm2_sk, dim3(NTOK / 128, DM_ / 128, 3), dim3(256), 0, stream,
                       A2, w_outT, P);
    hipLaunchKernelGGL(out_ln3, dim3(NTOK), dim3(256), 0, stream, P, out_g, out_b, out);
}

// Round 9
// 364.111 us; speedup vs baseline: 1.9071x; 1.9071x over previous
//
#include <hip/hip_runtime.h>

#define B_ 2
#define L_ 2048
#define HEADS_ 16
#define DH_ 64
#define DM_ 1024
#define DBI_ 2048
#define DPROJ_ 7168
#define NTOK (B_*L_)      // 4096
#define DCAT (DM_ + DBI_) // 3072

typedef __bf16 bf16;
typedef __attribute__((ext_vector_type(4))) __bf16 bf16x4;
typedef __attribute__((ext_vector_type(8))) __bf16 bf16x8;
typedef __attribute__((ext_vector_type(4))) float floatx4;

typedef __attribute__((address_space(1))) const void gptr_t;
typedef __attribute__((address_space(3))) void lptr_t;

__device__ __forceinline__ void g2l16(const void* g, void* l) {
    __builtin_amdgcn_global_load_lds((gptr_t*)g, (lptr_t*)l, 16, 0, 0);
}

// ---------------- fused weight transposes: w_in + w_out -> bf16 T ----------------
__global__ __launch_bounds__(256) void transpose_both(const float* __restrict__ w_in,
                                                      const float* __restrict__ w_out,
                                                      bf16* __restrict__ w_inT,
                                                      bf16* __restrict__ w_outT) {
    __shared__ float tile[32][33];
    int l = blockIdx.x;
    const float* in; bf16* outp; int R, C, bx, by;
    if (l < 7168) { in = w_in;  outp = w_inT;  R = DM_;  C = DPROJ_; bx = l % 224; by = l / 224; }
    else { l -= 7168; in = w_out; outp = w_outT; R = DCAT; C = DM_;   bx = l % 32;  by = l / 32; }
    int c0 = bx * 32, r0 = by * 32;
    int x = threadIdx.x & 31, y = threadIdx.x >> 5;
    for (int i = 0; i < 32; i += 8)
        tile[y + i][x] = in[(size_t)(r0 + y + i) * C + (c0 + x)];
    __syncthreads();
    for (int i = 0; i < 32; i += 8)
        outp[(size_t)(c0 + y + i) * R + (r0 + x)] = (bf16)tile[x][y + i];
}

// ---------------- in-LN + token shift -> xs (bf16), float4 vectorized ----------------
__global__ __launch_bounds__(256) void ln_shift(const float* __restrict__ x,
                                                const float* __restrict__ g,
                                                const float* __restrict__ bb,
                                                bf16* __restrict__ xs) {
    int tok = blockIdx.x;
    int b = tok >> 11, l = tok & 2047;
    int t = threadIdx.x;
    float4 v = ((const float4*)(x + (size_t)tok * DM_))[t];
    float s = v.x + v.y + v.z + v.w;
    float s2 = v.x * v.x + v.y * v.y + v.z * v.z + v.w * v.w;
    __shared__ float red[2][4];
    for (int o = 32; o; o >>= 1) { s += __shfl_xor(s, o); s2 += __shfl_xor(s2, o); }
    int w = t >> 6;
    if ((t & 63) == 0) { red[0][w] = s; red[1][w] = s2; }
    __syncthreads();
    s  = red[0][0] + red[0][1] + red[0][2] + red[0][3];
    s2 = red[1][0] + red[1][1] + red[1][2] + red[1][3];
    float mean = s * (1.f / DM_);
    float var  = s2 * (1.f / DM_) - mean * mean;
    float rstd = rsqrtf(var + 1e-5f);
    int c = t * 4;
    float4 gg = ((const float4*)g)[t];
    float4 bv = ((const float4*)bb)[t];
    bf16x4 y;
    y[0] = (bf16)((v.x - mean) * rstd * gg.x + bv.x);
    y[1] = (bf16)((v.y - mean) * rstd * gg.y + bv.y);
    y[2] = (bf16)((v.z - mean) * rstd * gg.z + bv.z);
    y[3] = (bf16)((v.w - mean) * rstd * gg.w + bv.w);
    int shift = (c < 256) ? 1 : ((c >= 896) ? 2 : 0);
    int dl = l + shift;
    if (dl < L_) *(bf16x4*)&xs[((size_t)b * L_ + dl) * DM_ + c] = y;
    if (l == 0 && shift) {
        bf16x4 z = {};
        *(bf16x4*)&xs[((size_t)b * L_) * DM_ + c] = z;
        if (shift == 2) *(bf16x4*)&xs[((size_t)b * L_ + 1) * DM_ + c] = z;
    }
}

// ---------------- GEMM1: 256x128 tile, ping-pong dbuf, 2 blocks/CU ----------------
// NOTE: (256,3) spills acc[4][8] (R8: WRITE_SIZE 57->841 MB, dur 87->400us).
// 104 VGPR needs the (256,2) budget.
__global__ __launch_bounds__(256, 2) void gemm1_k(const bf16* __restrict__ A,
                                                  const bf16* __restrict__ Bt,
                                                  bf16* __restrict__ C) {
    const int K = DM_, N = DPROJ_;
    int lin = blockIdx.x;                 // 896 blocks
    int chunk = lin >> 7, within = lin & 127;
    int m0 = (within >> 3) * 256;
    int n0 = (chunk * 8 + (within & 7)) * 128;
    __shared__ bf16 As[2][256 * 32];
    __shared__ bf16 Bs[2][128 * 32];
    int t = threadIdx.x, lane = t & 63, wave = t >> 6;
    int c = lane & 15, quad = lane >> 4;
    int wm = wave * 64;
    auto stage = [&](int k0, int bsel) {
        #pragma unroll
        for (int s = 0; s < 4; s++) {
            int f = s * 256 + t;
            int row = f >> 2, kp = (f & 3) * 8;
            g2l16(A + (size_t)(m0 + row) * K + k0 + kp, &As[bsel][f * 8]);
        }
        #pragma unroll
        for (int s = 0; s < 2; s++) {
            int f = s * 256 + t;
            int row = f >> 2, kp = (f & 3) * 8;
            g2l16(Bt + (size_t)(n0 + row) * K + k0 + kp, &Bs[bsel][f * 8]);
        }
    };
    floatx4 acc[4][8] = {};
    stage(0, 0);
    int buf = 0;
    for (int k0 = 0; k0 < K; k0 += 32) {
        __syncthreads();
        if (k0 + 32 < K) stage(k0 + 32, buf ^ 1);
        bf16x8 af[4], bfr[8];
        #pragma unroll
        for (int i = 0; i < 4; i++)
            af[i] = *(const bf16x8*)&As[buf][(wm + i * 16 + c) * 32 + quad * 8];
        #pragma unroll
        for (int j = 0; j < 8; j++)
            bfr[j] = *(const bf16x8*)&Bs[buf][(j * 16 + c) * 32 + quad * 8];
        #pragma unroll
        for (int i = 0; i < 4; i++)
            #pragma unroll
            for (int j = 0; j < 8; j++)
                acc[i][j] = __builtin_amdgcn_mfma_f32_16x16x32_bf16(af[i], bfr[j], acc[i][j], 0, 0, 0);
        buf ^= 1;
    }
    #pragma unroll
    for (int i = 0; i < 4; i++)
        #pragma unroll
        for (int j = 0; j < 8; j++)
            #pragma unroll
            for (int r = 0; r < 4; r++) {
                int row = m0 + wm + i * 16 + quad * 4 + r;
                int col = n0 + j * 16 + c;
                C[(size_t)row * N + col] = (bf16)acc[i][j][r];
            }
}

// ---------------- GEMM2 split-K: 128x128, dbuf (no waves bound - R7 config) ----------------
__global__ __launch_bounds__(256) void gemm2_sk(const bf16* __restrict__ A,
                                                const bf16* __restrict__ Bt,
                                                float* __restrict__ P) {
    const int ldA = DCAT, N = DM_;
    int m0 = blockIdx.x * 128, n0 = blockIdx.y * 128, kz = blockIdx.z;
    const bf16* Ak = A + kz * 1024;
    const bf16* Btk = Bt + kz * 1024;
    float* C = P + (size_t)kz * NTOK * DM_;
    __shared__ bf16 As[2][128 * 32];
    __shared__ bf16 Bs[2][128 * 32];
    int t = threadIdx.x, lane = t & 63, wave = t >> 6;
    int c = lane & 15, quad = lane >> 4;
    int wm = (wave >> 1) * 64, wn = (wave & 1) * 64;
    auto stage = [&](int k0, int bsel) {
        #pragma unroll
        for (int s = 0; s < 2; s++) {
            int f = s * 256 + t;
            int row = f >> 2, kp = (f & 3) * 8;
            g2l16(Ak + (size_t)(m0 + row) * ldA + k0 + kp, &As[bsel][f * 8]);
            g2l16(Btk + (size_t)(n0 + row) * ldA + k0 + kp, &Bs[bsel][f * 8]);
        }
    };
    floatx4 acc[4][4] = {};
    stage(0, 0);
    int buf = 0;
    for (int k0 = 0; k0 < 1024; k0 += 32) {
        __syncthreads();
        if (k0 + 32 < 1024) stage(k0 + 32, buf ^ 1);
        bf16x8 af[4], bfr[4];
        #pragma unroll
        for (int i = 0; i < 4; i++)
            af[i] = *(const bf16x8*)&As[buf][(wm + i * 16 + c) * 32 + quad * 8];
        #pragma unroll
        for (int j = 0; j < 4; j++)
            bfr[j] = *(const bf16x8*)&Bs[buf][(wn + j * 16 + c) * 32 + quad * 8];
        #pragma unroll
        for (int i = 0; i < 4; i++)
            #pragma unroll
            for (int j = 0; j < 4; j++)
                acc[i][j] = __builtin_amdgcn_mfma_f32_16x16x32_bf16(af[i], bfr[j], acc[i][j], 0, 0, 0);
        buf ^= 1;
    }
    #pragma unroll
    for (int i = 0; i < 4; i++)
        #pragma unroll
        for (int j = 0; j < 4; j++)
            #pragma unroll
            for (int r = 0; r < 4; r++) {
                int row = m0 + wm + i * 16 + quad * 4 + r;
                int col = n0 + wn + j * 16 + c;
                C[(size_t)row * N + col] = acc[i][j][r];
            }
}

// ---------------- mid-LN fused, vec8: h -> Qp,Kp,Vn packed + gated A2 ----------------
__global__ __launch_bounds__(256) void mid_ln_fused(const bf16* __restrict__ h,
                                                    const float* __restrict__ g,
                                                    const float* __restrict__ bb,
                                                    bf16* __restrict__ Qp,
                                                    bf16* __restrict__ Kp,
                                                    bf16* __restrict__ Vn,
                                                    bf16* __restrict__ A2) {
    int tok = blockIdx.x;
    int b = tok >> 11, l = tok & 2047;
    const bf16x8* hrow = (const bf16x8*)(h + (size_t)tok * DPROJ_);
    int t = threadIdx.x;
    int nch = (t < 128) ? 4 : 3;
    float v[4][8];
    float s = 0.f, s2 = 0.f;
    for (int i = 0; i < nch; i++) {
        bf16x8 hv = hrow[t + i * 256];
        #pragma unroll
        for (int j = 0; j < 8; j++) {
            float f = (float)hv[j];
            v[i][j] = f; s += f; s2 += f * f;
        }
    }
    __shared__ float red[2][4];
    for (int o = 32; o; o >>= 1) { s += __shfl_xor(s, o); s2 += __shfl_xor(s2, o); }
    int w = t >> 6;
    if ((t & 63) == 0) { red[0][w] = s; red[1][w] = s2; }
    __syncthreads();
    s  = red[0][0] + red[0][1] + red[0][2] + red[0][3];
    s2 = red[1][0] + red[1][1] + red[1][2] + red[1][3];
    float mean = s * (1.f / DPROJ_);
    float var  = s2 * (1.f / DPROJ_) - mean * mean;
    float rstd = rsqrtf(var + 1e-5f);
    for (int i = 0; i < nch; i++) {
        int c = (t + i * 256) * 8;
        float4 g0 = *(const float4*)&g[c],  g1 = *(const float4*)&g[c + 4];
        float4 b0 = *(const float4*)&bb[c], b1 = *(const float4*)&bb[c + 4];
        v[i][0] = (v[i][0] - mean) * rstd * g0.x + b0.x;
        v[i][1] = (v[i][1] - mean) * rstd * g0.y + b0.y;
        v[i][2] = (v[i][2] - mean) * rstd * g0.z + b0.z;
        v[i][3] = (v[i][3] - mean) * rstd * g0.w + b0.w;
        v[i][4] = (v[i][4] - mean) * rstd * g1.x + b1.x;
        v[i][5] = (v[i][5] - mean) * rstd * g1.y + b1.y;
        v[i][6] = (v[i][6] - mean) * rstd * g1.z + b1.z;
        v[i][7] = (v[i][7] - mean) * rstd * g1.w + b1.w;
    }
    bf16x8 o;
    {
        int cc = (t < 128) ? t * 8 : (t - 128) * 8;
        int hh = cc >> 6, d = cc & 63;
        #pragma unroll
        for (int j = 0; j < 8; j++) o[j] = (bf16)v[0][j];
        bf16* dst = (t < 128) ? Qp : Kp;
        *(bf16x8*)&dst[(((size_t)b * HEADS_ + hh) * L_ + l) * DH_ + d] = o;
    }
    if (t < 128) {
        int cc = t * 8, hh = cc >> 6, d = cc & 63;
        #pragma unroll
        for (int j = 0; j < 8; j++) o[j] = (bf16)v[1][j];
        *(bf16x8*)&Vn[(((size_t)b * HEADS_ + hh) * L_ + l) * DH_ + d] = o;
        #pragma unroll
        for (int j = 0; j < 8; j++) o[j] = (bf16)(v[2][j] * v[3][j]);
        *(bf16x8*)&A2[(size_t)tok * DCAT + DM_ + t * 8 + 1024] = o;
    } else {
        #pragma unroll
        for (int j = 0; j < 8; j++) o[j] = (bf16)(v[1][j] * v[2][j]);
        *(bf16x8*)&A2[(size_t)tok * DCAT + DM_ + (t - 128) * 8] = o;
    }
}

// ---------------- Vn [b,h,L,64] -> Vt [b,h,64,L] ----------------
__global__ __launch_bounds__(256) void vt_pack(const bf16* __restrict__ Vn,
                                               bf16* __restrict__ Vt) {
    __shared__ bf16 tile[32][33];
    int bh = blockIdx.z;
    const bf16* in = Vn + (size_t)bh * L_ * DH_;
    bf16* out = Vt + (size_t)bh * DH_ * L_;
    int l0 = blockIdx.x * 32, d0 = blockIdx.y * 32;
    int x = threadIdx.x & 31, y = threadIdx.x >> 5;
    for (int i = 0; i < 32; i += 8)
        tile[y + i][x] = in[(size_t)(l0 + y + i) * DH_ + d0 + x];
    __syncthreads();
    for (int i = 0; i < 32; i += 8)
        out[(size_t)(d0 + y + i) * L_ + l0 + x] = tile[x][y + i];
}

// ---------------- flash attention v4: fixed-max softmax ----------------
__global__ __launch_bounds__(256, 4) void attn4(const bf16* __restrict__ Qp,
                                                const bf16* __restrict__ Kp,
                                                const bf16* __restrict__ Vt,
                                                const float* __restrict__ slopes,
                                                bf16* __restrict__ A2) {
    int hd = blockIdx.y, b = blockIdx.z;
    int lin = blockIdx.x + 32 * blockIdx.y + 512 * blockIdx.z;
    int xr = blockIdx.x;
    int qt = ((lin >> 8) & 1) ? (31 - xr) : xr;
    int q0 = qt * 64;
    int t = threadIdx.x, lane = t & 63, wave = t >> 6;
    int quad = lane >> 4, c = lane & 15;
    __shared__ bf16 Ks[2 * 64 * 32];
    __shared__ bf16 Vs[2 * 64 * 32];
    __shared__ bf16 Ps[4][16 * 72];
    int bh = b * HEADS_ + hd;
    const bf16* Qb = Qp + (size_t)bh * L_ * DH_;
    const bf16* Kb = Kp + (size_t)bh * L_ * DH_;
    const bf16* Vb = Vt + (size_t)bh * DH_ * L_;
    const float LOG2E = 1.44269504f;
    float slopeL2 = slopes[hd] * LOG2E;
    const float qscale = 0.125f * LOG2E;

    bf16x8 qf[2];
    int qrow = q0 + wave * 16 + c;
    qf[0] = *(const bf16x8*)(Qb + (size_t)qrow * DH_ + quad * 8);
    qf[1] = *(const bf16x8*)(Qb + (size_t)qrow * DH_ + 32 + quad * 8);
    floatx4 accO[4] = {};
    float lsum[4];
    float mrow[4];
    int i_row0 = q0 + wave * 16 + quad * 4;
    #pragma unroll
    for (int r = 0; r < 4; r++) {
        lsum[r] = 0.f;
        mrow[r] = slopeL2 * (float)(i_row0 + r) + 20.0f;
    }

    int row = t >> 2, kp = (t & 3) * 8;
    bf16* pw = &Ps[wave][0];
    bf16* pwr = pw + (quad * 4) * 72 + c;
    for (int j0 = 0; j0 <= q0; j0 += 64) {
        #pragma unroll
        for (int s = 0; s < 2; s++) {
            g2l16(Kb + (size_t)(j0 + row) * DH_ + s * 32 + kp, &Ks[(s * 256 + t) * 8]);
            g2l16(Vb + (size_t)row * L_ + j0 + s * 32 + kp, &Vs[(s * 256 + t) * 8]);
        }
        __syncthreads();

        bool diag = (j0 == q0);
        #pragma unroll
        for (int nt = 0; nt < 4; nt++) {
            floatx4 sacc = {};
            bf16x8 kf0 = *(const bf16x8*)&Ks[(nt * 16 + c) * 32 + quad * 8];
            bf16x8 kf1 = *(const bf16x8*)&Ks[2048 + (nt * 16 + c) * 32 + quad * 8];
            sacc = __builtin_amdgcn_mfma_f32_16x16x32_bf16(qf[0], kf0, sacc, 0, 0, 0);
            sacc = __builtin_amdgcn_mfma_f32_16x16x32_bf16(qf[1], kf1, sacc, 0, 0, 0);
            int j = j0 + nt * 16 + c;
            float aj = slopeL2 * (float)j;
            #pragma unroll
            for (int r = 0; r < 4; r++) {
                float p = exp2f(fmaf(sacc[r], qscale, aj) - mrow[r]);
                if (diag) p = (j <= i_row0 + r) ? p : 0.f;
                lsum[r] += p;
                pwr[r * 72 + nt * 16] = (bf16)p;
            }
        }
        bf16x8 pf0 = *(const bf16x8*)&pw[c * 72 + quad * 8];
        bf16x8 pf1 = *(const bf16x8*)&pw[c * 72 + 32 + quad * 8];
        #pragma unroll
        for (int nt = 0; nt < 4; nt++) {
            bf16x8 vf0 = *(const bf16x8*)&Vs[(nt * 16 + c) * 32 + quad * 8];
            bf16x8 vf1 = *(const bf16x8*)&Vs[2048 + (nt * 16 + c) * 32 + quad * 8];
            accO[nt] = __builtin_amdgcn_mfma_f32_16x16x32_bf16(pf0, vf0, accO[nt], 0, 0, 0);
            accO[nt] = __builtin_amdgcn_mfma_f32_16x16x32_bf16(pf1, vf1, accO[nt], 0, 0, 0);
        }
        __syncthreads();
    }
    #pragma unroll
    for (int r = 0; r < 4; r++) {
        float l = lsum[r];
        l += __shfl_xor(l, 1);
        l += __shfl_xor(l, 2);
        l += __shfl_xor(l, 4);
        l += __shfl_xor(l, 8);
        lsum[r] = 1.f / l;
    }
    #pragma unroll
    for (int r = 0; r < 4; r++) {
        size_t orow = (size_t)b * L_ + q0 + wave * 16 + quad * 4 + r;
        #pragma unroll
        for (int nt = 0; nt < 4; nt++)
            A2[orow * DCAT + hd * DH_ + nt * 16 + c] = (bf16)(accO[nt][r] * lsum[r]);
    }
}

// ---------------- out-LN over sum of 3 contiguous split-K partials (float4) ----------------
__global__ __launch_bounds__(256) void out_ln3(const float* __restrict__ P,
                                               const float* __restrict__ g,
                                               const float* __restrict__ bb,
                                               float* __restrict__ out) {
    size_t base = (size_t)blockIdx.x * DM_;
    const size_t stride = (size_t)NTOK * DM_;
    int t = threadIdx.x;
    float4 a = *(const float4*)&P[base + t * 4];
    float4 b1 = *(const float4*)&P[base + stride + t * 4];
    float4 c1 = *(const float4*)&P[base + 2 * stride + t * 4];
    float4 v;
    v.x = a.x + b1.x + c1.x; v.y = a.y + b1.y + c1.y;
    v.z = a.z + b1.z + c1.z; v.w = a.w + b1.w + c1.w;
    float s = v.x + v.y + v.z + v.w;
    float s2 = v.x * v.x + v.y * v.y + v.z * v.z + v.w * v.w;
    __shared__ float red[2][4];
    for (int o = 32; o; o >>= 1) { s += __shfl_xor(s, o); s2 += __shfl_xor(s2, o); }
    int w = t >> 6;
    if ((t & 63) == 0) { red[0][w] = s; red[1][w] = s2; }
    __syncthreads();
    s  = red[0][0] + red[0][1] + red[0][2] + red[0][3];
    s2 = red[1][0] + red[1][1] + red[1][2] + red[1][3];
    float mean = s * (1.f / DM_);
    float var  = s2 * (1.f / DM_) - mean * mean;
    float rstd = rsqrtf(var + 1e-5f);
    float4 gg = ((const float4*)g)[t];
    float4 bv = ((const float4*)bb)[t];
    float4 y;
    y.x = (v.x - mean) * rstd * gg.x + bv.x;
    y.y = (v.y - mean) * rstd * gg.y + bv.y;
    y.z = (v.z - mean) * rstd * gg.z + bv.z;
    y.w = (v.w - mean) * rstd * gg.w + bv.w;
    *(float4*)&out[base + t * 4] = y;
}

extern "C" void kernel_launch(void* const* d_in, const int* in_sizes, int n_in,
                              void* d_out, int out_size, void* d_ws, size_t ws_size,
                              hipStream_t stream) {
    const float* x     = (const float*)d_in[0];
    const float* in_g  = (const float*)d_in[1];
    const float* in_b  = (const float*)d_in[2];
    const float* mid_g = (const float*)d_in[3];
    const float* mid_b = (const float*)d_in[4];
    const float* out_g = (const float*)d_in[5];
    const float* out_b = (const float*)d_in[6];
    const float* w_in  = (const float*)d_in[7];
    const float* w_out = (const float*)d_in[8];
    const float* slopes = (const float*)d_in[9];
    float* out = (float*)d_out;

    char* ws = (char*)d_ws;
    size_t off = 0;
    auto alloc = [&](size_t n) { char* p = ws + off; off += (n + 255) & ~(size_t)255; return p; };
    bf16* w_inT  = (bf16*)alloc((size_t)DPROJ_ * DM_ * 2);   // 14.7 MB
    bf16* w_outT = (bf16*)alloc((size_t)DM_ * DCAT * 2);     // 6.3 MB
    bf16* xs     = (bf16*)alloc((size_t)NTOK * DM_ * 2);     // 8.4 MB (reused as Vt)
    bf16* h      = (bf16*)alloc((size_t)NTOK * DPROJ_ * 2);  // 58.7 MB (reused: 3 contig f32 partials)
    bf16* A2     = (bf16*)alloc((size_t)NTOK * DCAT * 2);    // 25.2 MB
    bf16* Qp     = (bf16*)alloc((size_t)NTOK * DM_ * 2);     // 8.4 MB
    bf16* Kp     = (bf16*)alloc((size_t)NTOK * DM_ * 2);     // 8.4 MB
    bf16* Vn     = (bf16*)alloc((size_t)NTOK * DM_ * 2);     // 8.4 MB
    bf16* Vt = xs;            // xs dead after gemm1
    float* P = (float*)h;     // h dead after mid_ln_fused; gemm2 runs after attn

    hipLaunchKernelGGL(transpose_both, dim3(7168 + 3072), dim3(256), 0, stream,
                       w_in, w_out, w_inT, w_outT);
    hipLaunchKernelGGL(ln_shift, dim3(NTOK), dim3(256), 0, stream, x, in_g, in_b, xs);
    hipLaunchKernelGGL(gemm1_k, dim3(896), dim3(256), 0, stream, xs, w_inT, h);
    hipLaunchKernelGGL(mid_ln_fused, dim3(NTOK), dim3(256), 0, stream, h, mid_g, mid_b,
                       Qp, Kp, Vn, A2);
    hipLaunchKernelGGL(vt_pack, dim3(L_ / 32, DH_ / 32, B_ * HEADS_), dim3(256), 0, stream, Vn, Vt);
    hipLaunchKernelGGL(attn4, dim3(32, HEADS_, B_), dim3(256), 0, stream, Qp, Kp, Vt, slopes, A2);
    hipLaunchKernelGGL(gemm2_sk, dim3(NTOK / 128, DM_ / 128, 3), dim3(256), 0, stream,
                       A2, w_outT, P);
    hipLaunchKernelGGL(out_ln3, dim3(NTOK), dim3(256), 0, stream, P, out_g, out_b, out);
}

// Round 10
// 317.945 us; speedup vs baseline: 2.1840x; 1.1452x over previous
//
#include <hip/hip_runtime.h>

#define B_ 2
#define L_ 2048
#define HEADS_ 16
#define DH_ 64
#define DM_ 1024
#define DBI_ 2048
#define DPROJ_ 7168
#define NTOK (B_*L_)      // 4096
#define DCAT (DM_ + DBI_) // 3072

typedef __bf16 bf16;
typedef __attribute__((ext_vector_type(4))) __bf16 bf16x4;
typedef __attribute__((ext_vector_type(8))) __bf16 bf16x8;
typedef __attribute__((ext_vector_type(4))) float floatx4;

typedef __attribute__((address_space(1))) const void gptr_t;
typedef __attribute__((address_space(3))) void lptr_t;

__device__ __forceinline__ void g2l16(const void* g, void* l) {
    __builtin_amdgcn_global_load_lds((gptr_t*)g, (lptr_t*)l, 16, 0, 0);
}

// ---------------- fused weight transposes: w_in + w_out -> bf16 T ----------------
__global__ __launch_bounds__(256) void transpose_both(const float* __restrict__ w_in,
                                                      const float* __restrict__ w_out,
                                                      bf16* __restrict__ w_inT,
                                                      bf16* __restrict__ w_outT) {
    __shared__ float tile[32][33];
    int l = blockIdx.x;
    const float* in; bf16* outp; int R, C, bx, by;
    if (l < 7168) { in = w_in;  outp = w_inT;  R = DM_;  C = DPROJ_; bx = l % 224; by = l / 224; }
    else { l -= 7168; in = w_out; outp = w_outT; R = DCAT; C = DM_;   bx = l % 32;  by = l / 32; }
    int c0 = bx * 32, r0 = by * 32;
    int x = threadIdx.x & 31, y = threadIdx.x >> 5;
    for (int i = 0; i < 32; i += 8)
        tile[y + i][x] = in[(size_t)(r0 + y + i) * C + (c0 + x)];
    __syncthreads();
    for (int i = 0; i < 32; i += 8)
        outp[(size_t)(c0 + y + i) * R + (r0 + x)] = (bf16)tile[x][y + i];
}

// ---------------- in-LN + token shift -> xs (bf16), float4 vectorized ----------------
__global__ __launch_bounds__(256) void ln_shift(const float* __restrict__ x,
                                                const float* __restrict__ g,
                                                const float* __restrict__ bb,
                                                bf16* __restrict__ xs) {
    int tok = blockIdx.x;
    int b = tok >> 11, l = tok & 2047;
    int t = threadIdx.x;
    float4 v = ((const float4*)(x + (size_t)tok * DM_))[t];
    float s = v.x + v.y + v.z + v.w;
    float s2 = v.x * v.x + v.y * v.y + v.z * v.z + v.w * v.w;
    __shared__ float red[2][4];
    for (int o = 32; o; o >>= 1) { s += __shfl_xor(s, o); s2 += __shfl_xor(s2, o); }
    int w = t >> 6;
    if ((t & 63) == 0) { red[0][w] = s; red[1][w] = s2; }
    __syncthreads();
    s  = red[0][0] + red[0][1] + red[0][2] + red[0][3];
    s2 = red[1][0] + red[1][1] + red[1][2] + red[1][3];
    float mean = s * (1.f / DM_);
    float var  = s2 * (1.f / DM_) - mean * mean;
    float rstd = rsqrtf(var + 1e-5f);
    int c = t * 4;
    float4 gg = ((const float4*)g)[t];
    float4 bv = ((const float4*)bb)[t];
    bf16x4 y;
    y[0] = (bf16)((v.x - mean) * rstd * gg.x + bv.x);
    y[1] = (bf16)((v.y - mean) * rstd * gg.y + bv.y);
    y[2] = (bf16)((v.z - mean) * rstd * gg.z + bv.z);
    y[3] = (bf16)((v.w - mean) * rstd * gg.w + bv.w);
    int shift = (c < 256) ? 1 : ((c >= 896) ? 2 : 0);
    int dl = l + shift;
    if (dl < L_) *(bf16x4*)&xs[((size_t)b * L_ + dl) * DM_ + c] = y;
    if (l == 0 && shift) {
        bf16x4 z = {};
        *(bf16x4*)&xs[((size_t)b * L_) * DM_ + c] = z;
        if (shift == 2) *(bf16x4*)&xs[((size_t)b * L_ + 1) * DM_ + c] = z;
    }
}

// ---------------- GEMM1: 256x128 tile, ping-pong dbuf, 2 blocks/CU ----------------
// NOTE: (256,3) spills acc[4][8] (R8: WRITE_SIZE 57->841 MB). Keep (256,2).
__global__ __launch_bounds__(256, 2) void gemm1_k(const bf16* __restrict__ A,
                                                  const bf16* __restrict__ Bt,
                                                  bf16* __restrict__ C) {
    const int K = DM_, N = DPROJ_;
    int lin = blockIdx.x;                 // 896 blocks
    int chunk = lin >> 7, within = lin & 127;
    int m0 = (within >> 3) * 256;
    int n0 = (chunk * 8 + (within & 7)) * 128;
    __shared__ bf16 As[2][256 * 32];
    __shared__ bf16 Bs[2][128 * 32];
    int t = threadIdx.x, lane = t & 63, wave = t >> 6;
    int c = lane & 15, quad = lane >> 4;
    int wm = wave * 64;
    auto stage = [&](int k0, int bsel) {
        #pragma unroll
        for (int s = 0; s < 4; s++) {
            int f = s * 256 + t;
            int row = f >> 2, kp = (f & 3) * 8;
            g2l16(A + (size_t)(m0 + row) * K + k0 + kp, &As[bsel][f * 8]);
        }
        #pragma unroll
        for (int s = 0; s < 2; s++) {
            int f = s * 256 + t;
            int row = f >> 2, kp = (f & 3) * 8;
            g2l16(Bt + (size_t)(n0 + row) * K + k0 + kp, &Bs[bsel][f * 8]);
        }
    };
    floatx4 acc[4][8] = {};
    stage(0, 0);
    int buf = 0;
    for (int k0 = 0; k0 < K; k0 += 32) {
        __syncthreads();
        if (k0 + 32 < K) stage(k0 + 32, buf ^ 1);
        bf16x8 af[4], bfr[8];
        #pragma unroll
        for (int i = 0; i < 4; i++)
            af[i] = *(const bf16x8*)&As[buf][(wm + i * 16 + c) * 32 + quad * 8];
        #pragma unroll
        for (int j = 0; j < 8; j++)
            bfr[j] = *(const bf16x8*)&Bs[buf][(j * 16 + c) * 32 + quad * 8];
        #pragma unroll
        for (int i = 0; i < 4; i++)
            #pragma unroll
            for (int j = 0; j < 8; j++)
                acc[i][j] = __builtin_amdgcn_mfma_f32_16x16x32_bf16(af[i], bfr[j], acc[i][j], 0, 0, 0);
        buf ^= 1;
    }
    #pragma unroll
    for (int i = 0; i < 4; i++)
        #pragma unroll
        for (int j = 0; j < 8; j++)
            #pragma unroll
            for (int r = 0; r < 4; r++) {
                int row = m0 + wm + i * 16 + quad * 4 + r;
                int col = n0 + j * 16 + c;
                C[(size_t)row * N + col] = (bf16)acc[i][j][r];
            }
}

// ---------------- GEMM2 split-K: 128x128, dbuf ----------------
__global__ __launch_bounds__(256) void gemm2_sk(const bf16* __restrict__ A,
                                                const bf16* __restrict__ Bt,
                                                float* __restrict__ P) {
    const int ldA = DCAT, N = DM_;
    int m0 = blockIdx.x * 128, n0 = blockIdx.y * 128, kz = blockIdx.z;
    const bf16* Ak = A + kz * 1024;
    const bf16* Btk = Bt + kz * 1024;
    float* C = P + (size_t)kz * NTOK * DM_;
    __shared__ bf16 As[2][128 * 32];
    __shared__ bf16 Bs[2][128 * 32];
    int t = threadIdx.x, lane = t & 63, wave = t >> 6;
    int c = lane & 15, quad = lane >> 4;
    int wm = (wave >> 1) * 64, wn = (wave & 1) * 64;
    auto stage = [&](int k0, int bsel) {
        #pragma unroll
        for (int s = 0; s < 2; s++) {
            int f = s * 256 + t;
            int row = f >> 2, kp = (f & 3) * 8;
            g2l16(Ak + (size_t)(m0 + row) * ldA + k0 + kp, &As[bsel][f * 8]);
            g2l16(Btk + (size_t)(n0 + row) * ldA + k0 + kp, &Bs[bsel][f * 8]);
        }
    };
    floatx4 acc[4][4] = {};
    stage(0, 0);
    int buf = 0;
    for (int k0 = 0; k0 < 1024; k0 += 32) {
        __syncthreads();
        if (k0 + 32 < 1024) stage(k0 + 32, buf ^ 1);
        bf16x8 af[4], bfr[4];
        #pragma unroll
        for (int i = 0; i < 4; i++)
            af[i] = *(const bf16x8*)&As[buf][(wm + i * 16 + c) * 32 + quad * 8];
        #pragma unroll
        for (int j = 0; j < 4; j++)
            bfr[j] = *(const bf16x8*)&Bs[buf][(wn + j * 16 + c) * 32 + quad * 8];
        #pragma unroll
        for (int i = 0; i < 4; i++)
            #pragma unroll
            for (int j = 0; j < 4; j++)
                acc[i][j] = __builtin_amdgcn_mfma_f32_16x16x32_bf16(af[i], bfr[j], acc[i][j], 0, 0, 0);
        buf ^= 1;
    }
    #pragma unroll
    for (int i = 0; i < 4; i++)
        #pragma unroll
        for (int j = 0; j < 4; j++)
            #pragma unroll
            for (int r = 0; r < 4; r++) {
                int row = m0 + wm + i * 16 + quad * 4 + r;
                int col = n0 + wn + j * 16 + c;
                C[(size_t)row * N + col] = acc[i][j][r];
            }
}

// ---------------- mid-LN fused, vec8 with CONSTANT loop bounds ----------------
// R9 bug: loop bound nch=(t<128?4:3) was runtime-variant -> v[][] dynamically
// indexed -> demoted to scratch (+45us). Fix: constant bound 4, wave-uniform
// predicate (i<3 || t<128) on load/accumulate -> full unroll, v in VGPRs.
__global__ __launch_bounds__(256) void mid_ln_fused(const bf16* __restrict__ h,
                                                    const float* __restrict__ g,
                                                    const float* __restrict__ bb,
                                                    bf16* __restrict__ Qp,
                                                    bf16* __restrict__ Kp,
                                                    bf16* __restrict__ Vn,
                                                    bf16* __restrict__ A2) {
    int tok = blockIdx.x;
    int b = tok >> 11, l = tok & 2047;
    const bf16x8* hrow = (const bf16x8*)(h + (size_t)tok * DPROJ_);
    int t = threadIdx.x;
    float v[4][8];
    float s = 0.f, s2 = 0.f;
    #pragma unroll
    for (int i = 0; i < 4; i++) {
        if (i < 3 || t < 128) {
            bf16x8 hv = hrow[t + i * 256];
            #pragma unroll
            for (int j = 0; j < 8; j++) {
                float f = (float)hv[j];
                v[i][j] = f; s += f; s2 += f * f;
            }
        }
    }
    __shared__ float red[2][4];
    for (int o = 32; o; o >>= 1) { s += __shfl_xor(s, o); s2 += __shfl_xor(s2, o); }
    int w = t >> 6;
    if ((t & 63) == 0) { red[0][w] = s; red[1][w] = s2; }
    __syncthreads();
    s  = red[0][0] + red[0][1] + red[0][2] + red[0][3];
    s2 = red[1][0] + red[1][1] + red[1][2] + red[1][3];
    float mean = s * (1.f / DPROJ_);
    float var  = s2 * (1.f / DPROJ_) - mean * mean;
    float rstd = rsqrtf(var + 1e-5f);
    #pragma unroll
    for (int i = 0; i < 4; i++) {
        if (i < 3 || t < 128) {
            int c = (t + i * 256) * 8;
            float4 g0 = *(const float4*)&g[c],  g1 = *(const float4*)&g[c + 4];
            float4 b0 = *(const float4*)&bb[c], b1 = *(const float4*)&bb[c + 4];
            v[i][0] = (v[i][0] - mean) * rstd * g0.x + b0.x;
            v[i][1] = (v[i][1] - mean) * rstd * g0.y + b0.y;
            v[i][2] = (v[i][2] - mean) * rstd * g0.z + b0.z;
            v[i][3] = (v[i][3] - mean) * rstd * g0.w + b0.w;
            v[i][4] = (v[i][4] - mean) * rstd * g1.x + b1.x;
            v[i][5] = (v[i][5] - mean) * rstd * g1.y + b1.y;
            v[i][6] = (v[i][6] - mean) * rstd * g1.z + b1.z;
            v[i][7] = (v[i][7] - mean) * rstd * g1.w + b1.w;
        }
    }
    bf16x8 o;
    {
        int cc = (t < 128) ? t * 8 : (t - 128) * 8;
        int hh = cc >> 6, d = cc & 63;
        #pragma unroll
        for (int j = 0; j < 8; j++) o[j] = (bf16)v[0][j];
        bf16* dst = (t < 128) ? Qp : Kp;
        *(bf16x8*)&dst[(((size_t)b * HEADS_ + hh) * L_ + l) * DH_ + d] = o;
    }
    if (t < 128) {
        int cc = t * 8, hh = cc >> 6, d = cc & 63;
        #pragma unroll
        for (int j = 0; j < 8; j++) o[j] = (bf16)v[1][j];
        *(bf16x8*)&Vn[(((size_t)b * HEADS_ + hh) * L_ + l) * DH_ + d] = o;
        #pragma unroll
        for (int j = 0; j < 8; j++) o[j] = (bf16)(v[2][j] * v[3][j]);
        *(bf16x8*)&A2[(size_t)tok * DCAT + DM_ + t * 8 + 1024] = o;
    } else {
        #pragma unroll
        for (int j = 0; j < 8; j++) o[j] = (bf16)(v[1][j] * v[2][j]);
        *(bf16x8*)&A2[(size_t)tok * DCAT + DM_ + (t - 128) * 8] = o;
    }
}

// ---------------- Vn [b,h,L,64] -> Vt [b,h,64,L] ----------------
__global__ __launch_bounds__(256) void vt_pack(const bf16* __restrict__ Vn,
                                               bf16* __restrict__ Vt) {
    __shared__ bf16 tile[32][33];
    int bh = blockIdx.z;
    const bf16* in = Vn + (size_t)bh * L_ * DH_;
    bf16* out = Vt + (size_t)bh * DH_ * L_;
    int l0 = blockIdx.x * 32, d0 = blockIdx.y * 32;
    int x = threadIdx.x & 31, y = threadIdx.x >> 5;
    for (int i = 0; i < 32; i += 8)
        tile[y + i][x] = in[(size_t)(l0 + y + i) * DH_ + d0 + x];
    __syncthreads();
    for (int i = 0; i < 32; i += 8)
        out[(size_t)(d0 + y + i) * L_ + l0 + x] = tile[x][y + i];
}

// ---------------- flash attention v4: fixed-max softmax ----------------
__global__ __launch_bounds__(256, 4) void attn4(const bf16* __restrict__ Qp,
                                                const bf16* __restrict__ Kp,
                                                const bf16* __restrict__ Vt,
                                                const float* __restrict__ slopes,
                                                bf16* __restrict__ A2) {
    int hd = blockIdx.y, b = blockIdx.z;
    int lin = blockIdx.x + 32 * blockIdx.y + 512 * blockIdx.z;
    int xr = blockIdx.x;
    int qt = ((lin >> 8) & 1) ? (31 - xr) : xr;
    int q0 = qt * 64;
    int t = threadIdx.x, lane = t & 63, wave = t >> 6;
    int quad = lane >> 4, c = lane & 15;
    __shared__ bf16 Ks[2 * 64 * 32];
    __shared__ bf16 Vs[2 * 64 * 32];
    __shared__ bf16 Ps[4][16 * 72];
    int bh = b * HEADS_ + hd;
    const bf16* Qb = Qp + (size_t)bh * L_ * DH_;
    const bf16* Kb = Kp + (size_t)bh * L_ * DH_;
    const bf16* Vb = Vt + (size_t)bh * DH_ * L_;
    const float LOG2E = 1.44269504f;
    float slopeL2 = slopes[hd] * LOG2E;
    const float qscale = 0.125f * LOG2E;

    bf16x8 qf[2];
    int qrow = q0 + wave * 16 + c;
    qf[0] = *(const bf16x8*)(Qb + (size_t)qrow * DH_ + quad * 8);
    qf[1] = *(const bf16x8*)(Qb + (size_t)qrow * DH_ + 32 + quad * 8);
    floatx4 accO[4] = {};
    float lsum[4];
    float mrow[4];
    int i_row0 = q0 + wave * 16 + quad * 4;
    #pragma unroll
    for (int r = 0; r < 4; r++) {
        lsum[r] = 0.f;
        mrow[r] = slopeL2 * (float)(i_row0 + r) + 20.0f;
    }

    int row = t >> 2, kp = (t & 3) * 8;
    bf16* pw = &Ps[wave][0];
    bf16* pwr = pw + (quad * 4) * 72 + c;
    for (int j0 = 0; j0 <= q0; j0 += 64) {
        #pragma unroll
        for (int s = 0; s < 2; s++) {
            g2l16(Kb + (size_t)(j0 + row) * DH_ + s * 32 + kp, &Ks[(s * 256 + t) * 8]);
            g2l16(Vb + (size_t)row * L_ + j0 + s * 32 + kp, &Vs[(s * 256 + t) * 8]);
        }
        __syncthreads();

        bool diag = (j0 == q0);
        #pragma unroll
        for (int nt = 0; nt < 4; nt++) {
            floatx4 sacc = {};
            bf16x8 kf0 = *(const bf16x8*)&Ks[(nt * 16 + c) * 32 + quad * 8];
            bf16x8 kf1 = *(const bf16x8*)&Ks[2048 + (nt * 16 + c) * 32 + quad * 8];
            sacc = __builtin_amdgcn_mfma_f32_16x16x32_bf16(qf[0], kf0, sacc, 0, 0, 0);
            sacc = __builtin_amdgcn_mfma_f32_16x16x32_bf16(qf[1], kf1, sacc, 0, 0, 0);
            int j = j0 + nt * 16 + c;
            float aj = slopeL2 * (float)j;
            #pragma unroll
            for (int r = 0; r < 4; r++) {
                float p = exp2f(fmaf(sacc[r], qscale, aj) - mrow[r]);
                if (diag) p = (j <= i_row0 + r) ? p : 0.f;
                lsum[r] += p;
                pwr[r * 72 + nt * 16] = (bf16)p;
            }
        }
        bf16x8 pf0 = *(const bf16x8*)&pw[c * 72 + quad * 8];
        bf16x8 pf1 = *(const bf16x8*)&pw[c * 72 + 32 + quad * 8];
        #pragma unroll
        for (int nt = 0; nt < 4; nt++) {
            bf16x8 vf0 = *(const bf16x8*)&Vs[(nt * 16 + c) * 32 + quad * 8];
            bf16x8 vf1 = *(const bf16x8*)&Vs[2048 + (nt * 16 + c) * 32 + quad * 8];
            accO[nt] = __builtin_amdgcn_mfma_f32_16x16x32_bf16(pf0, vf0, accO[nt], 0, 0, 0);
            accO[nt] = __builtin_amdgcn_mfma_f32_16x16x32_bf16(pf1, vf1, accO[nt], 0, 0, 0);
        }
        __syncthreads();
    }
    #pragma unroll
    for (int r = 0; r < 4; r++) {
        float l = lsum[r];
        l += __shfl_xor(l, 1);
        l += __shfl_xor(l, 2);
        l += __shfl_xor(l, 4);
        l += __shfl_xor(l, 8);
        lsum[r] = 1.f / l;
    }
    #pragma unroll
    for (int r = 0; r < 4; r++) {
        size_t orow = (size_t)b * L_ + q0 + wave * 16 + quad * 4 + r;
        #pragma unroll
        for (int nt = 0; nt < 4; nt++)
            A2[orow * DCAT + hd * DH_ + nt * 16 + c] = (bf16)(accO[nt][r] * lsum[r]);
    }
}

// ---------------- out-LN over sum of 3 contiguous split-K partials (float4) ----------------
__global__ __launch_bounds__(256) void out_ln3(const float* __restrict__ P,
                                               const float* __restrict__ g,
                                               const float* __restrict__ bb,
                                               float* __restrict__ out) {
    size_t base = (size_t)blockIdx.x * DM_;
    const size_t stride = (size_t)NTOK * DM_;
    int t = threadIdx.x;
    float4 a = *(const float4*)&P[base + t * 4];
    float4 b1 = *(const float4*)&P[base + stride + t * 4];
    float4 c1 = *(const float4*)&P[base + 2 * stride + t * 4];
    float4 v;
    v.x = a.x + b1.x + c1.x; v.y = a.y + b1.y + c1.y;
    v.z = a.z + b1.z + c1.z; v.w = a.w + b1.w + c1.w;
    float s = v.x + v.y + v.z + v.w;
    float s2 = v.x * v.x + v.y * v.y + v.z * v.z + v.w * v.w;
    __shared__ float red[2][4];
    for (int o = 32; o; o >>= 1) { s += __shfl_xor(s, o); s2 += __shfl_xor(s2, o); }
    int w = t >> 6;
    if ((t & 63) == 0) { red[0][w] = s; red[1][w] = s2; }
    __syncthreads();
    s  = red[0][0] + red[0][1] + red[0][2] + red[0][3];
    s2 = red[1][0] + red[1][1] + red[1][2] + red[1][3];
    float mean = s * (1.f / DM_);
    float var  = s2 * (1.f / DM_) - mean * mean;
    float rstd = rsqrtf(var + 1e-5f);
    float4 gg = ((const float4*)g)[t];
    float4 bv = ((const float4*)bb)[t];
    float4 y;
    y.x = (v.x - mean) * rstd * gg.x + bv.x;
    y.y = (v.y - mean) * rstd * gg.y + bv.y;
    y.z = (v.z - mean) * rstd * gg.z + bv.z;
    y.w = (v.w - mean) * rstd * gg.w + bv.w;
    *(float4*)&out[base + t * 4] = y;
}

extern "C" void kernel_launch(void* const* d_in, const int* in_sizes, int n_in,
                              void* d_out, int out_size, void* d_ws, size_t ws_size,
                              hipStream_t stream) {
    const float* x     = (const float*)d_in[0];
    const float* in_g  = (const float*)d_in[1];
    const float* in_b  = (const float*)d_in[2];
    const float* mid_g = (const float*)d_in[3];
    const float* mid_b = (const float*)d_in[4];
    const float* out_g = (const float*)d_in[5];
    const float* out_b = (const float*)d_in[6];
    const float* w_in  = (const float*)d_in[7];
    const float* w_out = (const float*)d_in[8];
    const float* slopes = (const float*)d_in[9];
    float* out = (float*)d_out;

    char* ws = (char*)d_ws;
    size_t off = 0;
    auto alloc = [&](size_t n) { char* p = ws + off; off += (n + 255) & ~(size_t)255; return p; };
    bf16* w_inT  = (bf16*)alloc((size_t)DPROJ_ * DM_ * 2);   // 14.7 MB
    bf16* w_outT = (bf16*)alloc((size_t)DM_ * DCAT * 2);     // 6.3 MB
    bf16* xs     = (bf16*)alloc((size_t)NTOK * DM_ * 2);     // 8.4 MB (reused as Vt)
    bf16* h      = (bf16*)alloc((size_t)NTOK * DPROJ_ * 2);  // 58.7 MB (reused: 3 contig f32 partials)
    bf16* A2     = (bf16*)alloc((size_t)NTOK * DCAT * 2);    // 25.2 MB
    bf16* Qp     = (bf16*)alloc((size_t)NTOK * DM_ * 2);     // 8.4 MB
    bf16* Kp     = (bf16*)alloc((size_t)NTOK * DM_ * 2);     // 8.4 MB
    bf16* Vn     = (bf16*)alloc((size_t)NTOK * DM_ * 2);     // 8.4 MB
    bf16* Vt = xs;            // xs dead after gemm1
    float* P = (float*)h;     // h dead after mid_ln_fused; gemm2 runs after attn

    hipLaunchKernelGGL(transpose_both, dim3(7168 + 3072), dim3(256), 0, stream,
                       w_in, w_out, w_inT, w_outT);
    hipLaunchKernelGGL(ln_shift, dim3(NTOK), dim3(256), 0, stream, x, in_g, in_b, xs);
    hipLaunchKernelGGL(gemm1_k, dim3(896), dim3(256), 0, stream, xs, w_inT, h);
    hipLaunchKernelGGL(mid_ln_fused, dim3(NTOK), dim3(256), 0, stream, h, mid_g, mid_b,
                       Qp, Kp, Vn, A2);
    hipLaunchKernelGGL(vt_pack, dim3(L_ / 32, DH_ / 32, B_ * HEADS_), dim3(256), 0, stream, Vn, Vt);
    hipLaunchKernelGGL(attn4, dim3(32, HEADS_, B_), dim3(256), 0, stream, Qp, Kp, Vt, slopes, A2);
    hipLaunchKernelGGL(gemm2_sk, dim3(NTOK / 128, DM_ / 128, 3), dim3(256), 0, stream,
                       A2, w_outT, P);
    hipLaunchKernelGGL(out_ln3, dim3(NTOK), dim3(256), 0, stream, P, out_g, out_b, out);
}